// Round 12
// baseline (57.580 us; speedup 1.0000x reference)
//
#include <hip/hip_runtime.h>
#include <math.h>

#define NEG_SLOPE 0.01f
typedef float f32x4 __attribute__((ext_vector_type(4)));

// Single fused kernel. 16 lanes per dst node, 4 nodes per wave.
// Per group:
//   1. 16-ary parallel lower_bound over sorted dst -> segment start s
//   2. 16-wide scan -> segment end
//   3. a_dst from own row (dot + shfl reduce)
//   4. online softmax over chunks of 8 edges: each chunk gathers 8 src rows into
//      REGISTERS (lane q holds float4 slice q of every row); the same row data
//      yields the logit (dot with w[:F], 4-step shfl reduce) AND the weighted
//      accumulation. No precomputed a_src, no seg array, no LDS, no prep pass.
__global__ __launch_bounds__(256) void gat_one(
    const float* __restrict__ h, const float* __restrict__ w,
    const int* __restrict__ src, const int* __restrict__ dst,
    float* __restrict__ out, int N, int E)
{
    int gid   = blockIdx.x * blockDim.x + threadIdx.x;
    int node  = gid >> 4;
    if (node >= N) return;
    int lane  = threadIdx.x & 63;
    int q     = lane & 15;
    int gbase = lane & 48;              // group's base lane in the wave

    // independent loads first (compiler hoists; they hide under the search)
    float4 wsv = *(const float4*)(w + q * 4);        // w[:F] slice
    float4 wdv = *(const float4*)(w + 64 + q * 4);   // w[F:] slice
    float4 hn  = *(const float4*)(h + (long)node * 64 + q * 4);

    // ---- 16-ary lower_bound(dst, node): first i with dst[i] >= node ----
    int lo = 0, hi = E;
    while (hi - lo > 16) {
        int step = ((hi - lo) + 15) >> 4;            // ceil(range/16)
        int x  = lo + q * step;
        int pv = (x < hi) ? dst[x] : 0x7fffffff;
        unsigned long long b = __ballot(pv < node);
        int c = __popcll((b >> gbase) & 0xFFFFull);  // prefix-true count
        if (c == 0) { hi = lo; break; }              // dst[lo] >= node -> done
        int nl = lo + (c - 1) * step + 1;
        int nh = lo + c * step;
        lo = nl; hi = (nh < hi) ? nh : hi;           // new range size <= step
    }
    {   // final round: range <= 16
        int x  = lo + q;
        int pv = (x < hi) ? dst[x] : 0x7fffffff;
        unsigned long long b = __ballot(pv < node);
        lo += __popcll((b >> gbase) & 0xFFFFull);
    }
    const int s = lo;

    // ---- scan for segment end (dst[i] == node while inside) ----
    int eend = s;
    for (;;) {
        int x  = eend + q;
        int pv = (x < E) ? dst[x] : 0x7fffffff;
        unsigned long long b = __ballot(pv == node);
        int c = __popcll((b >> gbase) & 0xFFFFull);
        eend += c;
        if (c < 16) break;
    }

    // ---- a_dst = h[node] . w[F:] ----
    float pd = hn.x*wdv.x + hn.y*wdv.y + hn.z*wdv.z + hn.w*wdv.w;
    #pragma unroll
    for (int o = 8; o; o >>= 1) pd += __shfl_xor(pd, o);
    const float ad = pd;

    // ---- online softmax + accumulate, chunks of 8 edges in registers ----
    float m = -INFINITY, dsum = 0.0f;
    float4 acc = {0.f, 0.f, 0.f, 0.f};

    for (int c0 = s; c0 < eend; c0 += 8) {
        int cnt = eend - c0; if (cnt > 8) cnt = 8;   // group-uniform
        int sidx = c0 + q; if (sidx > E - 1) sidx = E - 1;
        int sq = src[sidx];                          // coalesced; lanes 8..15 prefetch next chunk

        float4 r0,r1,r2,r3,r4,r5,r6,r7;
        float  e0,e1,e2,e3,e4,e5,e6,e7;
        // Padded slots load the (L1-hot) own row and get e=-inf -> weight 0.
#define GATK(K, RK, EK) \
        { int sj = (K < cnt) ? __shfl(sq, gbase + K) : node; \
          RK = *(const float4*)(h + (long)sj * 64 + q * 4); \
          float p = RK.x*wsv.x + RK.y*wsv.y + RK.z*wsv.z + RK.w*wsv.w; \
          p += __shfl_xor(p, 1); p += __shfl_xor(p, 2); \
          p += __shfl_xor(p, 4); p += __shfl_xor(p, 8); \
          float t = p + ad; t = (t >= 0.f) ? t : NEG_SLOPE * t; \
          EK = (K < cnt) ? t : -INFINITY; }
        GATK(0,r0,e0) GATK(1,r1,e1) GATK(2,r2,e2) GATK(3,r3,e3)
        GATK(4,r4,e4) GATK(5,r5,e5) GATK(6,r6,e6) GATK(7,r7,e7)
#undef GATK

        float mc = fmaxf(fmaxf(fmaxf(e0,e1), fmaxf(e2,e3)),
                         fmaxf(fmaxf(e4,e5), fmaxf(e6,e7)));
        float mn = fmaxf(m, mc);
        float sc = __expf(m - mn);                   // first chunk: exp(-inf)=0
        acc.x *= sc; acc.y *= sc; acc.z *= sc; acc.w *= sc;
        dsum *= sc;
#define ACCK(RK, EK) \
        { float wk = __expf(EK - mn); dsum += wk; \
          acc.x = fmaf(wk, RK.x, acc.x); acc.y = fmaf(wk, RK.y, acc.y); \
          acc.z = fmaf(wk, RK.z, acc.z); acc.w = fmaf(wk, RK.w, acc.w); }
        ACCK(r0,e0) ACCK(r1,e1) ACCK(r2,e2) ACCK(r3,e3)
        ACCK(r4,e4) ACCK(r5,e5) ACCK(r6,e6) ACCK(r7,e7)
#undef ACCK
        m = mn;
    }

    float inv = (dsum > 0.f) ? (1.0f / dsum) : 0.0f; // empty segment -> zeros
    f32x4 v;
    v.x = acc.x * inv; v.y = acc.y * inv; v.z = acc.z * inv; v.w = acc.w * inv;
    __builtin_nontemporal_store(v, (f32x4*)(out + (long)node * 64 + q * 4));
}

extern "C" void kernel_launch(void* const* d_in, const int* in_sizes, int n_in,
                              void* d_out, int out_size, void* d_ws, size_t ws_size,
                              hipStream_t stream) {
    const float* h   = (const float*)d_in[0];
    const float* w   = (const float*)d_in[1];
    const int*   src = (const int*)d_in[2];
    const int*   dst = (const int*)d_in[3];
    float*       out = (float*)d_out;

    const int F = in_sizes[1] / 2;       // 64
    const int N = in_sizes[0] / F;       // 50000
    const int E = in_sizes[2];           // 800000

    gat_one<<<dim3((N * 16 + 255) / 256), dim3(256), 0, stream>>>(h, w, src, dst, out, N, E);
}